// Round 17
// baseline (421.043 us; speedup 1.0000x reference)
//
#include <hip/hip_runtime.h>
#include <hip/hip_bf16.h>

// Problem constants (from reference)
#define N_NODES 100000
#define N_EDGES (N_NODES * 32)
#define BATCH   1024
#define SPAN    40000u
#define MULT    7296u    // 2^32 mod 40000
#define FILL_B  (N_EDGES / 256)   // 12500 blocks for fill

// CSR bucket-sort parameters (R15-proven geometry)
#define NB_BKT 391               // ceil(100000 / 256) buckets of 256 nodes
#define EPB    4096              // edges per block in bucket passes
#define SBLK   782               // ceil(N_EDGES / EPB)
#define BKT_CAP 8960             // fixed bucket capacity: mean 8192 + 8.5 sigma

// History: R4 882 -> R11 bucket-CSR 733.8 -> R12 float4-gather 549 ->
// R13 readlane-layer2 498.7 -> R15 fixed-cap buckets 462.9 -> R16 KG LDS
// staging 456.4 -> R18 transposed dense 444.6 -> R23 composition 440.8 ->
// R24 scatter||gemm 434.2 -> R25 occupancy fixes 428.3 -> R26 fused
// argmax+topk 416.0. Parts-sum ~310 vs 416 => KG kernels are the gap:
// 1-wave blocks with 17KB LDS cap residency at ~9 blocks/CU (28% occ),
// nothing hides the stage_rows L2 latency. R27: halve the staging buffer
// (sn[32][65], two passes: rows 0..31 read by lanes<32, then re-stage
// rows 32..63 for lanes>=32) -> ~8.8KB/block -> ~2x residency. Per-lane
// score computed by identical kg_score_lds on identical row data ->
// bit-exact; softmax/argmax/rank/threefry verbatim; barriers free
// (1-wave blocks). Prune unchanged (dp-dn needs both rows resident).

// ---------------- Threefry-2x32 (exact JAX schedule) ----------------
__host__ __device__ inline void threefry2x32(unsigned k0, unsigned k1,
                                             unsigned x0, unsigned x1,
                                             unsigned* o0, unsigned* o1)
{
  unsigned ks2 = k0 ^ k1 ^ 0x1BD11BDAu;
  unsigned v0 = x0 + k0, v1 = x1 + k1;
#define RL(x,d) (((x) << (d)) | ((x) >> (32 - (d))))
#define G4(a,b,c,dd) \
  v0 += v1; v1 = RL(v1,a);  v1 ^= v0; \
  v0 += v1; v1 = RL(v1,b);  v1 ^= v0; \
  v0 += v1; v1 = RL(v1,c);  v1 ^= v0; \
  v0 += v1; v1 = RL(v1,dd); v1 ^= v0;
  G4(13,15,26,6)  v0 += k1;  v1 += ks2 + 1u;
  G4(17,29,16,24) v0 += ks2; v1 += k0 + 2u;
  G4(13,15,26,6)  v0 += k0;  v1 += k1 + 3u;
  G4(17,29,16,24) v0 += k1;  v1 += ks2 + 4u;
  G4(13,15,26,6)  v0 += ks2; v1 += k0 + 5u;
#undef G4
#undef RL
  *o0 = v0; *o1 = v1;
}

__device__ __forceinline__ float bcastf(float v, int l)
{
  return __int_as_float(__builtin_amdgcn_readlane(__float_as_int(v), l));
}

// ================= bucket counting sort -> CSR =================

// R15 primary-path init: fixed-capacity bucket bases/cursors.
__global__ void k_init_buckets(int* __restrict__ bbase, int* __restrict__ bcur)
{
  int i = blockIdx.x * 256 + threadIdx.x;
  if (i < NB_BKT) { bbase[i] = i * BKT_CAP; bcur[i] = i * BKT_CAP; }
}

// Fallback pass A1: per-block LDS histogram over dst>>8 -> global bhist.
__global__ __launch_bounds__(256) void k_bucket_hist(
    const int* __restrict__ edge, int* __restrict__ bhist)
{
  __shared__ int h[NB_BKT];
  for (int i = threadIdx.x; i < NB_BKT; i += 256) h[i] = 0;
  __syncthreads();
  int base = blockIdx.x * EPB;
  int cnt = N_EDGES - base; if (cnt > EPB) cnt = EPB;
  const int4* e4 = (const int4*)(edge + base);
  int nq = cnt >> 2;
  for (int i = threadIdx.x; i < nq; i += 256) {
    int4 v = e4[i];
    atomicAdd(&h[v.x >> 8], 1); atomicAdd(&h[v.y >> 8], 1);
    atomicAdd(&h[v.z >> 8], 1); atomicAdd(&h[v.w >> 8], 1);
  }
  __syncthreads();
  for (int i = threadIdx.x; i < NB_BKT; i += 256)
    if (h[i]) atomicAdd(&bhist[i], h[i]);
}

// Fallback pass A2: exclusive scan of 391 bucket counts; init cursors.
__global__ void k_scan_buckets(const int* __restrict__ bhist,
                               int* __restrict__ bbase, int* __restrict__ bcur)
{
  __shared__ int s[512];
  int t = threadIdx.x;
  s[t] = (t < NB_BKT) ? bhist[t] : 0;
  __syncthreads();
  for (int o = 1; o < 512; o <<= 1) {
    int u = (t >= o) ? s[t - o] : 0;
    __syncthreads();
    s[t] += u;
    __syncthreads();
  }
  if (t < NB_BKT) {
    int excl = s[t] - bhist[t];
    bbase[t] = excl;
    bcur[t]  = excl;
  }
}

// scatter body (shared): block bi counting-sorts its 4096 edges by bucket
// in LDS, reserves one contiguous run per bucket (1 atomicAdd on bcur
// with absolute offsets), copies runs out as PACKED 4B entries:
// (src_node << 8) | (dst & 255).  Staging: int buf + ushort bb2 (24KB).
__device__ __forceinline__ void scatter_body(
    int bi, int t, const int* __restrict__ edge, int* __restrict__ bcur,
    int* __restrict__ pairs,
    int* h, int* lbase, int* gbase, int* lcur, int* buf, unsigned short* bb2)
{
  for (int i = t; i < NB_BKT; i += 256) h[i] = 0;
  __syncthreads();
  int base = bi * EPB;
  int cnt = N_EDGES - base; if (cnt > EPB) cnt = EPB;
  const int4* e4 = (const int4*)(edge + base);
  int nq = cnt >> 2;
  for (int i = t; i < nq; i += 256) {
    int4 v = e4[i];
    atomicAdd(&h[v.x >> 8], 1); atomicAdd(&h[v.y >> 8], 1);
    atomicAdd(&h[v.z >> 8], 1); atomicAdd(&h[v.w >> 8], 1);
  }
  __syncthreads();
  // exclusive scan of h -> lbase, by wave 0 in 64-wide chunks
  if (t < 64) {
    int run = 0;
    for (int c = 0; c < NB_BKT; c += 64) {
      int idx = c + t;
      int v = (idx < NB_BKT) ? h[idx] : 0;
      int orig = v;
      for (int o = 1; o < 64; o <<= 1) {
        int u = __shfl_up(v, o);
        if (t >= o) v += u;
      }
      if (idx < NB_BKT) lbase[idx] = run + v - orig;
      run += __shfl(v, 63);
    }
  }
  __syncthreads();
  for (int i = t; i < NB_BKT; i += 256) lcur[i] = lbase[i];
  __syncthreads();
  // place packed entry + bucket id into staging, grouped by bucket
  for (int i = t; i < nq; i += 256) {
    int4 v = e4[i];
    int eid = base + (i << 2);
    int p;
    p = atomicAdd(&lcur[v.x >> 8], 1);
    buf[p] = (((eid + 0) >> 5) << 8) | (v.x & 255); bb2[p] = (unsigned short)(v.x >> 8);
    p = atomicAdd(&lcur[v.y >> 8], 1);
    buf[p] = (((eid + 1) >> 5) << 8) | (v.y & 255); bb2[p] = (unsigned short)(v.y >> 8);
    p = atomicAdd(&lcur[v.z >> 8], 1);
    buf[p] = (((eid + 2) >> 5) << 8) | (v.z & 255); bb2[p] = (unsigned short)(v.z >> 8);
    p = atomicAdd(&lcur[v.w >> 8], 1);
    buf[p] = (((eid + 3) >> 5) << 8) | (v.w & 255); bb2[p] = (unsigned short)(v.w >> 8);
  }
  __syncthreads();
  // reserve global space per bucket (one atomic per non-empty bucket)
  for (int i = t; i < NB_BKT; i += 256) {
    int c = lcur[i] - lbase[i];
    gbase[i] = (c > 0) ? atomicAdd(&bcur[i], c) : 0;
  }
  __syncthreads();
  // copy runs out (consecutive i in same bucket -> consecutive pos)
  for (int i = t; i < cnt; i += 256) {
    int b = bb2[i];
    pairs[gbase[b] + (i - lbase[b])] = buf[i];
  }
}

// standalone scatter (fallback path)
__global__ __launch_bounds__(256) void k_bucket_scatter(
    const int* __restrict__ edge, int* __restrict__ bcur,
    int* __restrict__ pairs)
{
  __shared__ int  h[NB_BKT];
  __shared__ int  lbase[NB_BKT];
  __shared__ int  gbase[NB_BKT];
  __shared__ int  lcur[NB_BKT];
  __shared__ int  buf[EPB];
  __shared__ unsigned short bb2[EPB];
  scatter_body(blockIdx.x, threadIdx.x, edge, bcur, pairs,
               h, lbase, gbase, lcur, buf, bb2);
}

// merged scatter + gemm (disjoint block ranges; A disjoint from pairs).
#define DGB 391   // 391 gemm blocks x 4 waves x 64 nodes = 100,096

__global__ __launch_bounds__(256, 5) void k_scatter_gemm(
    const int* __restrict__ edge, int* __restrict__ bcur,
    int* __restrict__ pairs, const float* __restrict__ x,
    const float* __restrict__ W, float* __restrict__ y)
{
  __shared__ int  h[NB_BKT];
  __shared__ int  lbase[NB_BKT];
  __shared__ int  gbase[NB_BKT];
  __shared__ int  lcur[NB_BKT];
  __shared__ int  buf[EPB];
  __shared__ unsigned short bb2[EPB];
  if (blockIdx.x < SBLK) {
    scatter_body(blockIdx.x, threadIdx.x, edge, bcur, pairs,
                 h, lbase, gbase, lcur, buf, bb2);
  } else {
    int lane = threadIdx.x & 63;
    int wv = (blockIdx.x - SBLK) * 4 + (threadIdx.x >> 6);
    int node = wv * 64 + lane;
    bool ok = node < N_NODES;
    const float4* x4 = (const float4*)(x + (size_t)node * 64);
    const float4* W4 = (const float4*)W;
    float acc[32];
#pragma unroll
    for (int o = 0; o < 32; ++o) acc[o] = 0.f;
#pragma unroll 1
    for (int j = 0; j < 16; ++j) {
      float4 xv = ok ? x4[j] : make_float4(0.f, 0.f, 0.f, 0.f);
#pragma unroll
      for (int o = 0; o < 32; ++o) {
        float4 wv4 = W4[o * 16 + j];
        acc[o] += wv4.x * xv.x;
        acc[o] += wv4.y * xv.y;
        acc[o] += wv4.z * xv.z;
        acc[o] += wv4.w * xv.w;
      }
    }
    if (ok) {
      float4* y4 = (float4*)(y + (size_t)node * 32);
#pragma unroll
      for (int k = 0; k < 8; ++k)
        y4[k] = make_float4(acc[4 * k], acc[4 * k + 1], acc[4 * k + 2], acc[4 * k + 3]);
    }
  }
}

// Pass B: one block per bucket (256 nodes), 1024 threads (R25-proven).
__global__ __launch_bounds__(1024) void k_bucket_csr(
    const int* __restrict__ bbase, const int* __restrict__ bcur,
    const int* __restrict__ pairs, int* __restrict__ csr,
    int* __restrict__ rowp, int* __restrict__ deg)
{
  __shared__ int nd[256], nb[256], nc[256];
  int b = blockIdx.x, t = threadIdx.x;
  int nb0 = b << 8;
  int ebase = bbase[b];
  int ecnt  = bcur[b] - ebase;
  if (t < 256) { nd[t] = 0; nc[t] = 0; }
  __syncthreads();
  for (int i = t; i < ecnt; i += 1024) {
    int pr = pairs[ebase + i];
    atomicAdd(&nd[pr & 255], 1);
  }
  __syncthreads();
  if (t < 256) nb[t] = nd[t];
  __syncthreads();
  for (int o = 1; o < 256; o <<= 1) {
    int u = (t >= o && t < 256) ? nb[t - o] : 0;
    __syncthreads();
    if (t < 256) nb[t] += u;
    __syncthreads();
  }
  if (t < 256) {
    int excl = nb[t] - nd[t];
    int node = nb0 + t;
    if (node < N_NODES) { rowp[node] = ebase + excl; deg[node] = nd[t]; }
    nb[t] = excl;
  }
  __syncthreads();
  for (int i = t; i < ecnt; i += 1024) {
    int pr = pairs[ebase + i];
    int l = pr & 255;
    int p = atomicAdd(&nc[l], 1);
    csr[ebase + nb[l] + p] = pr >> 8;    // src node id
  }
}

// float4 CSR gather: half-wave per node (R12-proven, unchanged).
__global__ __launch_bounds__(256) void k_gather_csr(
    const int* __restrict__ rowp, const int* __restrict__ deg,
    const int* __restrict__ csr, const float* __restrict__ src,
    float* __restrict__ out)
{
  int node = blockIdx.x * 8 + (threadIdx.x >> 5);
  int f = threadIdx.x & 31;
  int hb = threadIdx.x & 32;
  int sub = f >> 3;
  int q   = f & 7;
  int start = rowp[node];
  int dg = deg[node];
  const float4* src4 = (const float4*)src;
  float4 a0 = make_float4(0.f, 0.f, 0.f, 0.f);
  float4 a1 = make_float4(0.f, 0.f, 0.f, 0.f);
  for (int b0 = 0; b0 < dg; b0 += 32) {
    int idx = b0 + f;
    int e = (idx < dg) ? csr[start + idx] : -1;
#pragma unroll
    for (int j = 0; j < 8; j += 2) {
      int e0 = __shfl(e, hb + 4 * j + sub);
      int e1 = __shfl(e, hb + 4 * (j + 1) + sub);
      if (e0 >= 0) {
        float4 v = src4[(size_t)e0 * 8 + q];
        a0.x += v.x; a0.y += v.y; a0.z += v.z; a0.w += v.w;
      }
      if (e1 >= 0) {
        float4 v = src4[(size_t)e1 * 8 + q];
        a1.x += v.x; a1.y += v.y; a1.z += v.z; a1.w += v.w;
      }
    }
  }
  a0.x += a1.x; a0.y += a1.y; a0.z += a1.z; a0.w += a1.w;
  a0.x += __shfl_xor(a0.x, 8);  a0.y += __shfl_xor(a0.y, 8);
  a0.z += __shfl_xor(a0.z, 8);  a0.w += __shfl_xor(a0.w, 8);
  a0.x += __shfl_xor(a0.x, 16); a0.y += __shfl_xor(a0.y, 16);
  a0.z += __shfl_xor(a0.z, 16); a0.w += __shfl_xor(a0.w, 16);
  if (sub == 0) ((float4*)out)[(size_t)node * 8 + q] = a0;
}

// ---------------- legacy fused LL-fill + gemm (fallback paths) ----------
__global__ __launch_bounds__(256) void k_fill_gemm(
    const int* __restrict__ edge, int* __restrict__ head, int* __restrict__ next,
    int nsub, const float* __restrict__ x, const float* __restrict__ W,
    float* __restrict__ y)
{
  __shared__ float sw[32 * 65];
  if (blockIdx.x < FILL_B) {
    int e = blockIdx.x * 256 + threadIdx.x;
    int d = edge[e];
    int sub = e & (nsub - 1);
    int old = atomicExch(head + sub * N_NODES + d, e);
    next[e] = old;                       // coalesced by e
  } else {
    for (int t = threadIdx.x; t < 2048; t += 256) sw[(t >> 6) * 65 + (t & 63)] = W[t];
    __syncthreads();
    int i = (blockIdx.x - FILL_B) * 8 + (threadIdx.x >> 5);
    int f = threadIdx.x & 31;
    const float* xr = x + (size_t)i * 64;
    const float* wr = sw + f * 65;
    float acc = 0.f;
#pragma unroll
    for (int d = 0; d < 64; ++d) acc += xr[d] * wr[d];
    y[(size_t)i * 32 + f] = acc;
  }
}

// gather-aggregate via NSUB linked lists; half-wave (32 lanes) per node.
template<int NSUB>
__global__ __launch_bounds__(256) void k_gather_ll(
    const int* __restrict__ head, const int* __restrict__ next,
    const float* __restrict__ src, float* __restrict__ out,
    int* __restrict__ deg_out)
{
  int node = blockIdx.x * 8 + (threadIdx.x >> 5);
  int f = threadIdx.x & 31;
  int hb = threadIdx.x & 32;
  int e = (f < NSUB) ? head[f * N_NODES + node] : -1;
  float acc = 0.f;
  int cnt = 0;
  while (true) {
    int es[NSUB];
    bool any = false;
#pragma unroll
    for (int j = 0; j < NSUB; ++j) { es[j] = __shfl(e, hb + j); any |= (es[j] != -1); }
    if (!any) break;
    int en = -1;
    if (f < NSUB && e != -1) en = next[e];   // dependent chase load
#pragma unroll
    for (int j = 0; j < NSUB; ++j)
      if (es[j] != -1) { acc += src[(size_t)(es[j] >> 5) * 32 + f]; cnt++; }
    e = en;
  }
  out[(size_t)node * 32 + f] = acc;
  if (deg_out != nullptr && f == 0) deg_out[node] = cnt;
}

// ---------------- GCN dense kernels ----------------
// gemm/layer1: R18 node-per-lane transposed (proven).

__global__ __launch_bounds__(256, 4) void k_gemm64x32(
    const float* __restrict__ x, const float* __restrict__ W, float* __restrict__ y)
{
  int lane = threadIdx.x & 63;
  int wv = blockIdx.x * 4 + (threadIdx.x >> 6);
  int node = wv * 64 + lane;
  bool ok = node < N_NODES;
  const float4* x4 = (const float4*)(x + (size_t)node * 64);
  const float4* W4 = (const float4*)W;
  float acc[32];
#pragma unroll
  for (int o = 0; o < 32; ++o) acc[o] = 0.f;
#pragma unroll 1
  for (int j = 0; j < 16; ++j) {
    float4 xv = ok ? x4[j] : make_float4(0.f, 0.f, 0.f, 0.f);
#pragma unroll
    for (int o = 0; o < 32; ++o) {
      float4 wv4 = W4[o * 16 + j];
      acc[o] += wv4.x * xv.x;
      acc[o] += wv4.y * xv.y;
      acc[o] += wv4.z * xv.z;
      acc[o] += wv4.w * xv.w;
    }
  }
  if (ok) {
    float4* y4 = (float4*)(y + (size_t)node * 32);
#pragma unroll
    for (int k = 0; k < 8; ++k)
      y4[k] = make_float4(acc[4 * k], acc[4 * k + 1], acc[4 * k + 2], acc[4 * k + 3]);
  }
}

__global__ __launch_bounds__(256) void k_scatter(
    const int* __restrict__ edge, const float* __restrict__ src,
    float* __restrict__ acc, int* __restrict__ cnt)
{
  int e = blockIdx.x * 8 + (threadIdx.x >> 5);
  int f = threadIdx.x & 31;
  int d = edge[e];
  atomicAdd(acc + (size_t)d * 32 + f, src[(size_t)(e >> 5) * 32 + f]);
  if (cnt != nullptr && f == 0) atomicAdd(cnt + d, 1);
}

__global__ __launch_bounds__(256, 4) void k_layer1(
    const float* __restrict__ sum1, const int* __restrict__ cnt,
    const float* __restrict__ x, const float* __restrict__ W1r,
    const float* __restrict__ b1, float* __restrict__ h)
{
  int lane = threadIdx.x & 63;
  int wv = blockIdx.x * 4 + (threadIdx.x >> 6);
  int node = wv * 64 + lane;
  bool ok = node < N_NODES;
  const float4* x4 = (const float4*)(x + (size_t)node * 64);
  const float4* W4 = (const float4*)W1r;
  float acc[32];
#pragma unroll
  for (int o = 0; o < 32; ++o) acc[o] = 0.f;
#pragma unroll 1
  for (int j = 0; j < 16; ++j) {
    float4 xv = ok ? x4[j] : make_float4(0.f, 0.f, 0.f, 0.f);
#pragma unroll
    for (int o = 0; o < 32; ++o) {
      float4 wv4 = W4[o * 16 + j];
      acc[o] += wv4.x * xv.x;
      acc[o] += wv4.y * xv.y;
      acc[o] += wv4.z * xv.z;
      acc[o] += wv4.w * xv.w;
    }
  }
  if (ok) {
    float c = fmaxf((float)cnt[node], 1.f);
    const float4* s4 = (const float4*)(sum1 + (size_t)node * 32);
    float4* h4 = (float4*)(h + (size_t)node * 32);
#pragma unroll
    for (int k = 0; k < 8; ++k) {
      float4 sv = s4[k];
      float4 r;
      // order per element: (mean + sb) + acc  (== R7/R13 sequence)
      r.x = ((sv.x / c) + b1[4 * k + 0]) + acc[4 * k + 0];
      r.y = ((sv.y / c) + b1[4 * k + 1]) + acc[4 * k + 1];
      r.z = ((sv.z / c) + b1[4 * k + 2]) + acc[4 * k + 2];
      r.w = ((sv.w / c) + b1[4 * k + 3]) + acc[4 * k + 3];
      r.x = (r.x >= 0.f) ? r.x : 0.01f * r.x;
      r.y = (r.y >= 0.f) ? r.y : 0.01f * r.y;
      r.z = (r.z >= 0.f) ? r.z : 0.01f * r.z;
      r.w = (r.w >= 0.f) ? r.w : 0.01f * r.w;
      h4[k] = r;
    }
  }
}

// layer2 = R13-PROVEN readlane version VERBATIM (measured optimum 54us).
#define L2_BLOCKS 1250
#define L2_NPW    20
__global__ __launch_bounds__(256) void k_layer2(
    float* __restrict__ A, float* __restrict__ B, const int* __restrict__ cnt,
    const float* __restrict__ W2l, const float* __restrict__ W2r,
    const float* __restrict__ b2)
{
  int lane = threadIdx.x & 63;
  int gw = blockIdx.x * 4 + (threadIdx.x >> 6);
  float wl[32], wr[32];
#pragma unroll
  for (int f = 0; f < 32; ++f) { wl[f] = W2l[lane * 32 + f]; wr[f] = W2r[lane * 32 + f]; }
  float bb = b2[lane];
  int n0 = gw * L2_NPW;
#pragma unroll 1
  for (int i = n0; i < n0 + L2_NPW; ++i) {
    float c = fmaxf((float)cnt[i], 1.f);
    float vin;
    if (lane < 32) vin = B[(size_t)i * 32 + lane] / c;
    else           vin = A[(size_t)i * 32 + (lane - 32)];
    float acc = 0.f, acc2 = 0.f;
#pragma unroll
    for (int f = 0; f < 32; ++f) {
      acc  += bcastf(vin, f)      * wl[f];
      acc2 += bcastf(vin, 32 + f) * wr[f];
    }
    float t = (acc + bb) + acc2;
    float s = t * t;
#pragma unroll
    for (int o = 32; o > 0; o >>= 1) s += __shfl_xor(s, o);
    float g = t / fmaxf(sqrtf(s), 1e-12f);
    if (lane < 32) A[(size_t)i * 32 + lane]        = g;
    else           B[(size_t)i * 32 + (lane - 32)] = g;
  }
}

// ---------------- KG phase ----------------

__device__ inline float kg_score_lds(const float* __restrict__ row,
                                     const float* sp, const float* su)
{
  float acc = 0.f;
#pragma unroll
  for (int d = 0; d < 64; ++d) {
    float t = sp[d] * row[d];
    t = (t >= 0.f) ? t : 0.01f * t;
    acc += t * su[d];
  }
  return acc;
}

__device__ inline float wave_softmax(float acc)
{
  float m = acc;
#pragma unroll
  for (int o = 32; o > 0; o >>= 1) m = fmaxf(m, __shfl_xor(m, o));
  float e = expf(acc - m);
  float Z = e;
#pragma unroll
  for (int o = 32; o > 0; o >>= 1) Z += __shfl_xor(Z, o);
  return e / Z;
}

__device__ inline void load_row(const float* glo, const float* ghi, int node,
                                int lane, float* smem)
{
  smem[lane] = (lane < 32) ? glo[(size_t)node * 32 + lane]
                           : ghi[(size_t)node * 32 + (lane - 32)];
}

// stage 64 neighbor rows (nb per-lane) into sn[64][65], coalesced.
// (used by k_kg_prune)
__device__ inline void stage_rows(const float* __restrict__ glo,
                                  const float* __restrict__ ghi,
                                  int nb, int lane, float* sn)
{
#pragma unroll
  for (int j = 0; j < 64; ++j) {
    int rj = __builtin_amdgcn_readlane(nb, j);
    float v = (lane < 32) ? glo[(size_t)rj * 32 + lane]
                          : ghi[(size_t)rj * 32 + (lane - 32)];
    sn[j * 65 + lane] = v;
  }
}

// R27: stage 32 rows (jbase..jbase+31) into sn[32][65], coalesced.
__device__ inline void stage_rows32(const float* __restrict__ glo,
                                    const float* __restrict__ ghi,
                                    int nb, int lane, float* sn, int jbase)
{
#pragma unroll
  for (int j = 0; j < 32; ++j) {
    int rj = __builtin_amdgcn_readlane(nb, jbase + j);
    float v = (lane < 32) ? glo[(size_t)rj * 32 + lane]
                          : ghi[(size_t)rj * 32 + (lane - 32)];
    sn[j * 65 + lane] = v;
  }
}

// R27: compute per-lane score with split staging (32-row buffer, 2 passes).
// Per-lane value identical to the full-staging version -> bit-exact.
__device__ inline float split_score(const float* __restrict__ glo,
                                    const float* __restrict__ ghi,
                                    int nb, int lane, float* sn,
                                    const float* sp, const float* su)
{
  bool lo = lane < 32;
  stage_rows32(glo, ghi, nb, lane, sn, 0);
  __syncthreads();
  float sc = 0.f;
  if (lo) sc = kg_score_lds(sn + lane * 65, sp, su);
  __syncthreads();
  stage_rows32(glo, ghi, nb, lane, sn, 32);
  __syncthreads();
  if (!lo) sc = kg_score_lds(sn + (lane - 32) * 65, sp, su);
  return sc;
}

// R26/R27 fused KG selection kernel.  blocks [0,1024): argmax phase
// followed in-register by topk2 var=0 (pidx=nbr=sel, a-keys, writes
// candA + logA + one_hop_log).  blocks [1024,2048): topk2 var=1
// (pidx=pvec, nbr=u, c-keys, writes candB).  R27: split staging
// (sn[32][65], ~8.8KB LDS -> ~2x block residency).  All selection
// arithmetic verbatim from the R14/R16-proven kernels.
__global__ __launch_bounds__(64) void k_kg_fused(
    const float* __restrict__ glo, const float* __restrict__ ghi,
    const int* __restrict__ users, const int* __restrict__ pvec,
    const int* __restrict__ adj,
    unsigned a1a, unsigned a1b, unsigned a2a, unsigned a2b,
    unsigned c1a, unsigned c1b, unsigned c2a, unsigned c2b,
    int* __restrict__ candA, float* __restrict__ logA,
    int* __restrict__ candB, float* __restrict__ one_hop_log)
{
  int b = blockIdx.x & (BATCH - 1);
  int var = blockIdx.x >> 10;
  int lane = threadIdx.x;
  int u = users[b];
  __shared__ float su[64], sp[64];
  __shared__ float sn[32 * 65];
  load_row(glo, ghi, u, lane, su);

  if (var == 1) {
    // ---- topk2 var=1 path (pos2) ----
    int pidx = pvec[b];
    load_row(glo, ghi, pidx, lane, sp);
    int nb = adj[(size_t)u * 64 + lane];
    float sc = split_score(glo, ghi, nb, lane, sn, sp, su);
    float sm = wave_softmax(sc);
    int r = 0;
#pragma unroll
    for (int j = 0; j < 64; ++j) {
      float sj = bcastf(sm, j);
      if (sj > sm || (sj == sm && j < lane)) ++r;
    }
    if (r < 32) {
      int cand = nb;
      unsigned jj = (unsigned)(b * 32 + r);
      unsigned h0, h1, l0, l1;
      threefry2x32(c1a, c1b, 0u, jj, &h0, &h1);
      threefry2x32(c2a, c2b, 0u, jj, &l0, &l1);
      unsigned hi = h0 ^ h1, lo2 = l0 ^ l1;
      unsigned rnd = ((hi % SPAN) * MULT + (lo2 % SPAN)) % SPAN;
      if (cand > 39999 || cand < 0) cand = (int)rnd;
      candB[b * 32 + r] = cand;
    }
  } else {
    // ---- phase 1: argmax ----
    int pb = pvec[b];
    load_row(glo, ghi, pb, lane, sp);
    int nb = adj[(size_t)pb * 64 + lane];
    float sc = split_score(glo, ghi, nb, lane, sn, sp, su);
    float sm = wave_softmax(sc);
    float v = sm; int i = lane;
#pragma unroll
    for (int o = 32; o > 0; o >>= 1) {
      float ov = __shfl_xor(v, o); int oi = __shfl_xor(i, o);
      if (ov > v || (ov == v && oi < i)) { v = ov; i = oi; }
    }
    float smw = __shfl(sm, i);
    int sel = __shfl(nb, i);
    if (lane == 0) one_hop_log[b] = logf(smw);
    // ---- phase 2: topk2 var=0 with pidx = nbr = sel ----
    __syncthreads();
    load_row(glo, ghi, sel, lane, sp);
    int nb2 = adj[(size_t)sel * 64 + lane];
    float sc2 = split_score(glo, ghi, nb2, lane, sn, sp, su);
    float sm2 = wave_softmax(sc2);
    int r = 0;
#pragma unroll
    for (int j = 0; j < 64; ++j) {
      float sj = bcastf(sm2, j);
      if (sj > sm2 || (sj == sm2 && j < lane)) ++r;
    }
    if (r < 32) {
      int cand = nb2;
      logA[b * 32 + r] = logf(sm2);
      unsigned jj = (unsigned)(b * 32 + r);
      unsigned h0, h1, l0, l1;
      threefry2x32(a1a, a1b, 0u, jj, &h0, &h1);
      threefry2x32(a2a, a2b, 0u, jj, &l0, &l1);
      unsigned hi = h0 ^ h1, lo2 = l0 ^ l1;
      unsigned rnd = ((hi % SPAN) * MULT + (lo2 % SPAN)) % SPAN;
      if (cand > 39999 || cand < 0) cand = (int)rnd;
      candA[b * 32 + r] = cand;
    }
  }
}

// R16: prune with LDS-staged disc rows (dp rows j<32, dn rows j>=32).
__global__ __launch_bounds__(64) void k_kg_prune(
    const float* __restrict__ disc, const int* __restrict__ users,
    const int* __restrict__ cand, const float* __restrict__ two_log,
    const int* __restrict__ pos2, const float* __restrict__ one_log,
    float* __restrict__ out, int k, int* __restrict__ p_next)
{
  int b = blockIdx.x, lane = threadIdx.x;
  __shared__ float su[64];
  __shared__ float sd[64 * 65];
  su[lane] = disc[(size_t)users[b] * 64 + lane];
  int pr = (lane < 32) ? pos2[b * 32 + lane] : cand[b * 32 + (lane - 32)];
#pragma unroll
  for (int j = 0; j < 64; ++j) {
    int rj = __builtin_amdgcn_readlane(pr, j);
    sd[j * 65 + lane] = disc[(size_t)rj * 64 + lane];
  }
  __syncthreads();
  float r = 1e30f;
  if (lane < 32) {
    const float* dp = sd + lane * 65;
    const float* dn = sd + (32 + lane) * 65;
    float acc = 0.f;
#pragma unroll
    for (int d = 0; d < 64; ++d) acc += su[d] * (dp[d] - dn[d]);
    r = acc;
  }
  float v = r; int i = lane;
#pragma unroll
  for (int o = 32; o > 0; o >>= 1) {
    float ov = __shfl_xor(v, o); int oi = __shfl_xor(i, o);
    if (ov < v || (ov == v && oi < i)) { v = ov; i = oi; }
  }
  if (lane == 0) {
    int gn = cand[b * 32 + i];
    float gl = two_log[b * 32 + i] + one_log[b];
    out[k * BATCH + b]             = (float)gn;
    out[2 * BATCH + k * BATCH + b] = gl;
    p_next[b] = gn;
  }
}

// ---------------- launch ----------------
extern "C" void kernel_launch(void* const* d_in, const int* in_sizes, int n_in,
                              void* d_out, int out_size, void* d_ws, size_t ws_size,
                              hipStream_t stream)
{
  const float* x    = (const float*)d_in[0];
  const float* W1l  = (const float*)d_in[1];
  const float* W1r  = (const float*)d_in[2];
  const float* b1   = (const float*)d_in[3];
  const float* W2l  = (const float*)d_in[4];
  const float* W2r  = (const float*)d_in[5];
  const float* b2   = (const float*)d_in[6];
  const float* disc = (const float*)d_in[7];
  const int*   users= (const int*)d_in[8];
  const int*   pos  = (const int*)d_in[9];
  const int*   adj  = (const int*)d_in[10];
  const int*   edge = (const int*)d_in[11];
  float* out = (float*)d_out;

  char* w = (char*)d_ws;
  // R24 layout (A disjoint so gemm can overlap the bucket chain):
  //   [0, 14,013,440)            csr (src ids grouped by dst, bucket gaps)
  //   [14,013,440, +400,000)     row_ptr (absolute)
  //   [14,413,440, +400,000)     deg
  //   [14,813,440, +2,048)       bbase
  //   [14,815,488, +2,048)       bcur
  //   [14,817,536, +12,800,000)  A  (gemm output; later layer1 output)
  //   [27,617,536, +14,013,440)  packed pairs; B ALIASES pairs[0:12.8M)
  //   [41,630,976, +405,504)     KG buffers   => NEED_FIX = 42,036,480
  const size_t NEED_FIX = 42036480;
  const size_t NEED_CSR = 39617792;   // fallback: scan-based tight layout
  float *A, *B;
  char* bb;

  if (ws_size >= NEED_FIX) {
    int*  csr   = (int*)(w);
    int*  rowp  = (int*)(w + 14013440);
    int*  deg   = (int*)(w + 14413440);
    int*  bbase = (int*)(w + 14813440);
    int*  bcur  = (int*)(w + 14815488);
    A = (float*)(w + 14817536);
    int*  pairs = (int*)(w + 27617536);
    B = (float*)(w + 27617536);
    bb = w + 41630976;
    k_init_buckets<<<2, 256, 0, stream>>>(bbase, bcur);
    // merged: scatter (blocks 0..SBLK) || gemm x@W1l^T -> A (blocks SBLK..)
    k_scatter_gemm<<<SBLK + DGB, 256, 0, stream>>>(edge, bcur, pairs, x, W1l, A);
    k_bucket_csr<<<NB_BKT, 1024, 0, stream>>>(bbase, bcur, pairs, csr, rowp, deg);
    // pairs dead from here; gather#1 may write B (aliases pairs)
    k_gather_csr<<<N_NODES / 8, 256, 0, stream>>>(rowp, deg, csr, A, B);
    k_layer1<<<DGB, 256, 0, stream>>>(B, deg, x, W1r, b1, A);
    k_gather_csr<<<N_NODES / 8, 256, 0, stream>>>(rowp, deg, csr, A, B);
    k_layer2<<<L2_BLOCKS, 256, 0, stream>>>(A, B, deg, W2l, W2r, b2);
  } else if (ws_size >= NEED_CSR) {
    // fallback: R13-style scan-based tight CSR (A aliases pairs; serial gemm)
    int*  csr   = (int*)(w);
    int*  rowp  = (int*)(w + 12800000);
    int*  deg   = (int*)(w + 13200000);
    int*  bhist = (int*)(w + 13600000);
    int*  bbase = (int*)(w + 13604096);
    int*  bcur  = (int*)(w + 13608192);
    int*  pairs = (int*)(w + 13612288);
    A = (float*)(w + 13612288);
    B = (float*)(w + 26412288);
    bb = w + 39212288;
    hipMemsetAsync(bhist, 0, 4096, stream);
    k_bucket_hist<<<SBLK, 256, 0, stream>>>(edge, bhist);
    k_scan_buckets<<<1, 512, 0, stream>>>(bhist, bbase, bcur);
    k_bucket_scatter<<<SBLK, 256, 0, stream>>>(edge, bcur, pairs);
    k_bucket_csr<<<NB_BKT, 1024, 0, stream>>>(bbase, bcur, pairs, csr, rowp, deg);
    k_gemm64x32<<<DGB, 256, 0, stream>>>(x, W1l, A);
    k_gather_csr<<<N_NODES / 8, 256, 0, stream>>>(rowp, deg, csr, A, B);
    k_layer1<<<DGB, 256, 0, stream>>>(B, deg, x, W1r, b1, A);
    k_gather_csr<<<N_NODES / 8, 256, 0, stream>>>(rowp, deg, csr, A, B);
    k_layer2<<<L2_BLOCKS, 256, 0, stream>>>(A, B, deg, W2l, W2r, b2);
  } else {
    // fallback: proven atomic-scatter path (R4)
    int* cnt = (int*)w;
    A = (float*)(w + 409600);
    B = (float*)(w + 13209600);
    bb = w + 26009600;
    hipMemsetAsync(cnt, 0, 400000, stream);
    hipMemsetAsync(B, 0, 12800000, stream);
    k_gemm64x32<<<DGB, 256, 0, stream>>>(x, W1l, A);
    k_scatter<<<N_EDGES / 8, 256, 0, stream>>>(edge, A, B, cnt);
    k_layer1<<<DGB, 256, 0, stream>>>(B, cnt, x, W1r, b1, A);
    hipMemsetAsync(B, 0, 12800000, stream);
    k_scatter<<<N_EDGES / 8, 256, 0, stream>>>(edge, A, B, nullptr);
    k_layer2<<<L2_BLOCKS, 256, 0, stream>>>(A, B, cnt, W2l, W2r, b2);
  }

  int*   p_cur       = (int*)(bb);
  float* one_hop_log = (float*)(bb + 8192);
  int*   cand        = (int*)(bb + 12288);
  float* two_log     = (float*)(bb + 143360);
  int*   pos2        = (int*)(bb + 274432);

  // --- KG walk, K_STEP = 2 (R26: fused argmax+topk per k) ---
  for (int k = 0; k < 2; ++k) {
    unsigned f0, f1, a1a, a1b, a2a, a2b, c1a, c1b, c2a, c2b;
    threefry2x32(0u, 123u, 0u, (unsigned)(2 * k), &f0, &f1);
    threefry2x32(f0, f1, 0u, 0u, &a1a, &a1b);
    threefry2x32(f0, f1, 0u, 1u, &a2a, &a2b);
    threefry2x32(0u, 123u, 0u, (unsigned)(2 * k + 1), &f0, &f1);
    threefry2x32(f0, f1, 0u, 0u, &c1a, &c1b);
    threefry2x32(f0, f1, 0u, 1u, &c2a, &c2b);

    const int* pvec = (k == 0) ? pos : p_cur;
    k_kg_fused<<<2 * BATCH, 64, 0, stream>>>(A, B, users, pvec, adj,
                                             a1a, a1b, a2a, a2b, c1a, c1b, c2a, c2b,
                                             cand, two_log, pos2, one_hop_log);
    k_kg_prune<<<BATCH, 64, 0, stream>>>(disc, users, cand, two_log, pos2,
                                         one_hop_log, out, k, p_cur);
  }
}

// Round 18
// 415.314 us; speedup vs baseline: 1.0138x; 1.0138x over previous
//
#include <hip/hip_runtime.h>
#include <hip/hip_bf16.h>

// Problem constants (from reference)
#define N_NODES 100000
#define N_EDGES (N_NODES * 32)
#define BATCH   1024
#define SPAN    40000u
#define MULT    7296u    // 2^32 mod 40000
#define FILL_B  (N_EDGES / 256)   // 12500 blocks for fill

// CSR bucket-sort parameters (R15-proven geometry)
#define NB_BKT 391               // ceil(100000 / 256) buckets of 256 nodes
#define EPB    4096              // edges per block in bucket passes
#define SBLK   782               // ceil(N_EDGES / EPB)
#define BKT_CAP 8960             // fixed bucket capacity: mean 8192 + 8.5 sigma

// History: R4 882 -> R11 bucket-CSR 733.8 -> R12 float4-gather 549 ->
// R13 readlane-layer2 498.7 -> R15 fixed-cap buckets 462.9 -> R16 KG LDS
// staging 456.4 -> R18 transposed dense 444.6 -> R23 composition 440.8 ->
// R24 scatter||gemm 434.2 -> R25 occupancy fixes 428.3 -> R26 fused
// argmax+topk 416.0 (BEST) -> R27 split-staging 421.0 (REGRESSION:
// occupancy gain < added barriers + halved read-parallelism during score
// loops; same lesson as the R18-R22 layer2 saga). R28: REVERT k_kg_fused
// to the R26 full-staging form verbatim. Every component is now the
// best-measured variant across 27 rounds; no new mechanisms.

// ---------------- Threefry-2x32 (exact JAX schedule) ----------------
__host__ __device__ inline void threefry2x32(unsigned k0, unsigned k1,
                                             unsigned x0, unsigned x1,
                                             unsigned* o0, unsigned* o1)
{
  unsigned ks2 = k0 ^ k1 ^ 0x1BD11BDAu;
  unsigned v0 = x0 + k0, v1 = x1 + k1;
#define RL(x,d) (((x) << (d)) | ((x) >> (32 - (d))))
#define G4(a,b,c,dd) \
  v0 += v1; v1 = RL(v1,a);  v1 ^= v0; \
  v0 += v1; v1 = RL(v1,b);  v1 ^= v0; \
  v0 += v1; v1 = RL(v1,c);  v1 ^= v0; \
  v0 += v1; v1 = RL(v1,dd); v1 ^= v0;
  G4(13,15,26,6)  v0 += k1;  v1 += ks2 + 1u;
  G4(17,29,16,24) v0 += ks2; v1 += k0 + 2u;
  G4(13,15,26,6)  v0 += k0;  v1 += k1 + 3u;
  G4(17,29,16,24) v0 += k1;  v1 += ks2 + 4u;
  G4(13,15,26,6)  v0 += ks2; v1 += k0 + 5u;
#undef G4
#undef RL
  *o0 = v0; *o1 = v1;
}

__device__ __forceinline__ float bcastf(float v, int l)
{
  return __int_as_float(__builtin_amdgcn_readlane(__float_as_int(v), l));
}

// ================= bucket counting sort -> CSR =================

// R15 primary-path init: fixed-capacity bucket bases/cursors.
__global__ void k_init_buckets(int* __restrict__ bbase, int* __restrict__ bcur)
{
  int i = blockIdx.x * 256 + threadIdx.x;
  if (i < NB_BKT) { bbase[i] = i * BKT_CAP; bcur[i] = i * BKT_CAP; }
}

// Fallback pass A1: per-block LDS histogram over dst>>8 -> global bhist.
__global__ __launch_bounds__(256) void k_bucket_hist(
    const int* __restrict__ edge, int* __restrict__ bhist)
{
  __shared__ int h[NB_BKT];
  for (int i = threadIdx.x; i < NB_BKT; i += 256) h[i] = 0;
  __syncthreads();
  int base = blockIdx.x * EPB;
  int cnt = N_EDGES - base; if (cnt > EPB) cnt = EPB;
  const int4* e4 = (const int4*)(edge + base);
  int nq = cnt >> 2;
  for (int i = threadIdx.x; i < nq; i += 256) {
    int4 v = e4[i];
    atomicAdd(&h[v.x >> 8], 1); atomicAdd(&h[v.y >> 8], 1);
    atomicAdd(&h[v.z >> 8], 1); atomicAdd(&h[v.w >> 8], 1);
  }
  __syncthreads();
  for (int i = threadIdx.x; i < NB_BKT; i += 256)
    if (h[i]) atomicAdd(&bhist[i], h[i]);
}

// Fallback pass A2: exclusive scan of 391 bucket counts; init cursors.
__global__ void k_scan_buckets(const int* __restrict__ bhist,
                               int* __restrict__ bbase, int* __restrict__ bcur)
{
  __shared__ int s[512];
  int t = threadIdx.x;
  s[t] = (t < NB_BKT) ? bhist[t] : 0;
  __syncthreads();
  for (int o = 1; o < 512; o <<= 1) {
    int u = (t >= o) ? s[t - o] : 0;
    __syncthreads();
    s[t] += u;
    __syncthreads();
  }
  if (t < NB_BKT) {
    int excl = s[t] - bhist[t];
    bbase[t] = excl;
    bcur[t]  = excl;
  }
}

// scatter body (shared): block bi counting-sorts its 4096 edges by bucket
// in LDS, reserves one contiguous run per bucket (1 atomicAdd on bcur
// with absolute offsets), copies runs out as PACKED 4B entries:
// (src_node << 8) | (dst & 255).  Staging: int buf + ushort bb2 (24KB).
__device__ __forceinline__ void scatter_body(
    int bi, int t, const int* __restrict__ edge, int* __restrict__ bcur,
    int* __restrict__ pairs,
    int* h, int* lbase, int* gbase, int* lcur, int* buf, unsigned short* bb2)
{
  for (int i = t; i < NB_BKT; i += 256) h[i] = 0;
  __syncthreads();
  int base = bi * EPB;
  int cnt = N_EDGES - base; if (cnt > EPB) cnt = EPB;
  const int4* e4 = (const int4*)(edge + base);
  int nq = cnt >> 2;
  for (int i = t; i < nq; i += 256) {
    int4 v = e4[i];
    atomicAdd(&h[v.x >> 8], 1); atomicAdd(&h[v.y >> 8], 1);
    atomicAdd(&h[v.z >> 8], 1); atomicAdd(&h[v.w >> 8], 1);
  }
  __syncthreads();
  // exclusive scan of h -> lbase, by wave 0 in 64-wide chunks
  if (t < 64) {
    int run = 0;
    for (int c = 0; c < NB_BKT; c += 64) {
      int idx = c + t;
      int v = (idx < NB_BKT) ? h[idx] : 0;
      int orig = v;
      for (int o = 1; o < 64; o <<= 1) {
        int u = __shfl_up(v, o);
        if (t >= o) v += u;
      }
      if (idx < NB_BKT) lbase[idx] = run + v - orig;
      run += __shfl(v, 63);
    }
  }
  __syncthreads();
  for (int i = t; i < NB_BKT; i += 256) lcur[i] = lbase[i];
  __syncthreads();
  // place packed entry + bucket id into staging, grouped by bucket
  for (int i = t; i < nq; i += 256) {
    int4 v = e4[i];
    int eid = base + (i << 2);
    int p;
    p = atomicAdd(&lcur[v.x >> 8], 1);
    buf[p] = (((eid + 0) >> 5) << 8) | (v.x & 255); bb2[p] = (unsigned short)(v.x >> 8);
    p = atomicAdd(&lcur[v.y >> 8], 1);
    buf[p] = (((eid + 1) >> 5) << 8) | (v.y & 255); bb2[p] = (unsigned short)(v.y >> 8);
    p = atomicAdd(&lcur[v.z >> 8], 1);
    buf[p] = (((eid + 2) >> 5) << 8) | (v.z & 255); bb2[p] = (unsigned short)(v.z >> 8);
    p = atomicAdd(&lcur[v.w >> 8], 1);
    buf[p] = (((eid + 3) >> 5) << 8) | (v.w & 255); bb2[p] = (unsigned short)(v.w >> 8);
  }
  __syncthreads();
  // reserve global space per bucket (one atomic per non-empty bucket)
  for (int i = t; i < NB_BKT; i += 256) {
    int c = lcur[i] - lbase[i];
    gbase[i] = (c > 0) ? atomicAdd(&bcur[i], c) : 0;
  }
  __syncthreads();
  // copy runs out (consecutive i in same bucket -> consecutive pos)
  for (int i = t; i < cnt; i += 256) {
    int b = bb2[i];
    pairs[gbase[b] + (i - lbase[b])] = buf[i];
  }
}

// standalone scatter (fallback path)
__global__ __launch_bounds__(256) void k_bucket_scatter(
    const int* __restrict__ edge, int* __restrict__ bcur,
    int* __restrict__ pairs)
{
  __shared__ int  h[NB_BKT];
  __shared__ int  lbase[NB_BKT];
  __shared__ int  gbase[NB_BKT];
  __shared__ int  lcur[NB_BKT];
  __shared__ int  buf[EPB];
  __shared__ unsigned short bb2[EPB];
  scatter_body(blockIdx.x, threadIdx.x, edge, bcur, pairs,
               h, lbase, gbase, lcur, buf, bb2);
}

// merged scatter + gemm (disjoint block ranges; A disjoint from pairs).
#define DGB 391   // 391 gemm blocks x 4 waves x 64 nodes = 100,096

__global__ __launch_bounds__(256, 5) void k_scatter_gemm(
    const int* __restrict__ edge, int* __restrict__ bcur,
    int* __restrict__ pairs, const float* __restrict__ x,
    const float* __restrict__ W, float* __restrict__ y)
{
  __shared__ int  h[NB_BKT];
  __shared__ int  lbase[NB_BKT];
  __shared__ int  gbase[NB_BKT];
  __shared__ int  lcur[NB_BKT];
  __shared__ int  buf[EPB];
  __shared__ unsigned short bb2[EPB];
  if (blockIdx.x < SBLK) {
    scatter_body(blockIdx.x, threadIdx.x, edge, bcur, pairs,
                 h, lbase, gbase, lcur, buf, bb2);
  } else {
    int lane = threadIdx.x & 63;
    int wv = (blockIdx.x - SBLK) * 4 + (threadIdx.x >> 6);
    int node = wv * 64 + lane;
    bool ok = node < N_NODES;
    const float4* x4 = (const float4*)(x + (size_t)node * 64);
    const float4* W4 = (const float4*)W;
    float acc[32];
#pragma unroll
    for (int o = 0; o < 32; ++o) acc[o] = 0.f;
#pragma unroll 1
    for (int j = 0; j < 16; ++j) {
      float4 xv = ok ? x4[j] : make_float4(0.f, 0.f, 0.f, 0.f);
#pragma unroll
      for (int o = 0; o < 32; ++o) {
        float4 wv4 = W4[o * 16 + j];
        acc[o] += wv4.x * xv.x;
        acc[o] += wv4.y * xv.y;
        acc[o] += wv4.z * xv.z;
        acc[o] += wv4.w * xv.w;
      }
    }
    if (ok) {
      float4* y4 = (float4*)(y + (size_t)node * 32);
#pragma unroll
      for (int k = 0; k < 8; ++k)
        y4[k] = make_float4(acc[4 * k], acc[4 * k + 1], acc[4 * k + 2], acc[4 * k + 3]);
    }
  }
}

// Pass B: one block per bucket (256 nodes), 1024 threads (R25-proven).
__global__ __launch_bounds__(1024) void k_bucket_csr(
    const int* __restrict__ bbase, const int* __restrict__ bcur,
    const int* __restrict__ pairs, int* __restrict__ csr,
    int* __restrict__ rowp, int* __restrict__ deg)
{
  __shared__ int nd[256], nb[256], nc[256];
  int b = blockIdx.x, t = threadIdx.x;
  int nb0 = b << 8;
  int ebase = bbase[b];
  int ecnt  = bcur[b] - ebase;
  if (t < 256) { nd[t] = 0; nc[t] = 0; }
  __syncthreads();
  for (int i = t; i < ecnt; i += 1024) {
    int pr = pairs[ebase + i];
    atomicAdd(&nd[pr & 255], 1);
  }
  __syncthreads();
  if (t < 256) nb[t] = nd[t];
  __syncthreads();
  for (int o = 1; o < 256; o <<= 1) {
    int u = (t >= o && t < 256) ? nb[t - o] : 0;
    __syncthreads();
    if (t < 256) nb[t] += u;
    __syncthreads();
  }
  if (t < 256) {
    int excl = nb[t] - nd[t];
    int node = nb0 + t;
    if (node < N_NODES) { rowp[node] = ebase + excl; deg[node] = nd[t]; }
    nb[t] = excl;
  }
  __syncthreads();
  for (int i = t; i < ecnt; i += 1024) {
    int pr = pairs[ebase + i];
    int l = pr & 255;
    int p = atomicAdd(&nc[l], 1);
    csr[ebase + nb[l] + p] = pr >> 8;    // src node id
  }
}

// float4 CSR gather: half-wave per node (R12-proven, unchanged).
__global__ __launch_bounds__(256) void k_gather_csr(
    const int* __restrict__ rowp, const int* __restrict__ deg,
    const int* __restrict__ csr, const float* __restrict__ src,
    float* __restrict__ out)
{
  int node = blockIdx.x * 8 + (threadIdx.x >> 5);
  int f = threadIdx.x & 31;
  int hb = threadIdx.x & 32;
  int sub = f >> 3;
  int q   = f & 7;
  int start = rowp[node];
  int dg = deg[node];
  const float4* src4 = (const float4*)src;
  float4 a0 = make_float4(0.f, 0.f, 0.f, 0.f);
  float4 a1 = make_float4(0.f, 0.f, 0.f, 0.f);
  for (int b0 = 0; b0 < dg; b0 += 32) {
    int idx = b0 + f;
    int e = (idx < dg) ? csr[start + idx] : -1;
#pragma unroll
    for (int j = 0; j < 8; j += 2) {
      int e0 = __shfl(e, hb + 4 * j + sub);
      int e1 = __shfl(e, hb + 4 * (j + 1) + sub);
      if (e0 >= 0) {
        float4 v = src4[(size_t)e0 * 8 + q];
        a0.x += v.x; a0.y += v.y; a0.z += v.z; a0.w += v.w;
      }
      if (e1 >= 0) {
        float4 v = src4[(size_t)e1 * 8 + q];
        a1.x += v.x; a1.y += v.y; a1.z += v.z; a1.w += v.w;
      }
    }
  }
  a0.x += a1.x; a0.y += a1.y; a0.z += a1.z; a0.w += a1.w;
  a0.x += __shfl_xor(a0.x, 8);  a0.y += __shfl_xor(a0.y, 8);
  a0.z += __shfl_xor(a0.z, 8);  a0.w += __shfl_xor(a0.w, 8);
  a0.x += __shfl_xor(a0.x, 16); a0.y += __shfl_xor(a0.y, 16);
  a0.z += __shfl_xor(a0.z, 16); a0.w += __shfl_xor(a0.w, 16);
  if (sub == 0) ((float4*)out)[(size_t)node * 8 + q] = a0;
}

// ---------------- legacy fused LL-fill + gemm (fallback paths) ----------
__global__ __launch_bounds__(256) void k_fill_gemm(
    const int* __restrict__ edge, int* __restrict__ head, int* __restrict__ next,
    int nsub, const float* __restrict__ x, const float* __restrict__ W,
    float* __restrict__ y)
{
  __shared__ float sw[32 * 65];
  if (blockIdx.x < FILL_B) {
    int e = blockIdx.x * 256 + threadIdx.x;
    int d = edge[e];
    int sub = e & (nsub - 1);
    int old = atomicExch(head + sub * N_NODES + d, e);
    next[e] = old;                       // coalesced by e
  } else {
    for (int t = threadIdx.x; t < 2048; t += 256) sw[(t >> 6) * 65 + (t & 63)] = W[t];
    __syncthreads();
    int i = (blockIdx.x - FILL_B) * 8 + (threadIdx.x >> 5);
    int f = threadIdx.x & 31;
    const float* xr = x + (size_t)i * 64;
    const float* wr = sw + f * 65;
    float acc = 0.f;
#pragma unroll
    for (int d = 0; d < 64; ++d) acc += xr[d] * wr[d];
    y[(size_t)i * 32 + f] = acc;
  }
}

// gather-aggregate via NSUB linked lists; half-wave (32 lanes) per node.
template<int NSUB>
__global__ __launch_bounds__(256) void k_gather_ll(
    const int* __restrict__ head, const int* __restrict__ next,
    const float* __restrict__ src, float* __restrict__ out,
    int* __restrict__ deg_out)
{
  int node = blockIdx.x * 8 + (threadIdx.x >> 5);
  int f = threadIdx.x & 31;
  int hb = threadIdx.x & 32;
  int e = (f < NSUB) ? head[f * N_NODES + node] : -1;
  float acc = 0.f;
  int cnt = 0;
  while (true) {
    int es[NSUB];
    bool any = false;
#pragma unroll
    for (int j = 0; j < NSUB; ++j) { es[j] = __shfl(e, hb + j); any |= (es[j] != -1); }
    if (!any) break;
    int en = -1;
    if (f < NSUB && e != -1) en = next[e];   // dependent chase load
#pragma unroll
    for (int j = 0; j < NSUB; ++j)
      if (es[j] != -1) { acc += src[(size_t)(es[j] >> 5) * 32 + f]; cnt++; }
    e = en;
  }
  out[(size_t)node * 32 + f] = acc;
  if (deg_out != nullptr && f == 0) deg_out[node] = cnt;
}

// ---------------- GCN dense kernels ----------------
// gemm/layer1: R18 node-per-lane transposed (proven).

__global__ __launch_bounds__(256, 4) void k_gemm64x32(
    const float* __restrict__ x, const float* __restrict__ W, float* __restrict__ y)
{
  int lane = threadIdx.x & 63;
  int wv = blockIdx.x * 4 + (threadIdx.x >> 6);
  int node = wv * 64 + lane;
  bool ok = node < N_NODES;
  const float4* x4 = (const float4*)(x + (size_t)node * 64);
  const float4* W4 = (const float4*)W;
  float acc[32];
#pragma unroll
  for (int o = 0; o < 32; ++o) acc[o] = 0.f;
#pragma unroll 1
  for (int j = 0; j < 16; ++j) {
    float4 xv = ok ? x4[j] : make_float4(0.f, 0.f, 0.f, 0.f);
#pragma unroll
    for (int o = 0; o < 32; ++o) {
      float4 wv4 = W4[o * 16 + j];
      acc[o] += wv4.x * xv.x;
      acc[o] += wv4.y * xv.y;
      acc[o] += wv4.z * xv.z;
      acc[o] += wv4.w * xv.w;
    }
  }
  if (ok) {
    float4* y4 = (float4*)(y + (size_t)node * 32);
#pragma unroll
    for (int k = 0; k < 8; ++k)
      y4[k] = make_float4(acc[4 * k], acc[4 * k + 1], acc[4 * k + 2], acc[4 * k + 3]);
  }
}

__global__ __launch_bounds__(256) void k_scatter(
    const int* __restrict__ edge, const float* __restrict__ src,
    float* __restrict__ acc, int* __restrict__ cnt)
{
  int e = blockIdx.x * 8 + (threadIdx.x >> 5);
  int f = threadIdx.x & 31;
  int d = edge[e];
  atomicAdd(acc + (size_t)d * 32 + f, src[(size_t)(e >> 5) * 32 + f]);
  if (cnt != nullptr && f == 0) atomicAdd(cnt + d, 1);
}

__global__ __launch_bounds__(256, 4) void k_layer1(
    const float* __restrict__ sum1, const int* __restrict__ cnt,
    const float* __restrict__ x, const float* __restrict__ W1r,
    const float* __restrict__ b1, float* __restrict__ h)
{
  int lane = threadIdx.x & 63;
  int wv = blockIdx.x * 4 + (threadIdx.x >> 6);
  int node = wv * 64 + lane;
  bool ok = node < N_NODES;
  const float4* x4 = (const float4*)(x + (size_t)node * 64);
  const float4* W4 = (const float4*)W1r;
  float acc[32];
#pragma unroll
  for (int o = 0; o < 32; ++o) acc[o] = 0.f;
#pragma unroll 1
  for (int j = 0; j < 16; ++j) {
    float4 xv = ok ? x4[j] : make_float4(0.f, 0.f, 0.f, 0.f);
#pragma unroll
    for (int o = 0; o < 32; ++o) {
      float4 wv4 = W4[o * 16 + j];
      acc[o] += wv4.x * xv.x;
      acc[o] += wv4.y * xv.y;
      acc[o] += wv4.z * xv.z;
      acc[o] += wv4.w * xv.w;
    }
  }
  if (ok) {
    float c = fmaxf((float)cnt[node], 1.f);
    const float4* s4 = (const float4*)(sum1 + (size_t)node * 32);
    float4* h4 = (float4*)(h + (size_t)node * 32);
#pragma unroll
    for (int k = 0; k < 8; ++k) {
      float4 sv = s4[k];
      float4 r;
      // order per element: (mean + sb) + acc  (== R7/R13 sequence)
      r.x = ((sv.x / c) + b1[4 * k + 0]) + acc[4 * k + 0];
      r.y = ((sv.y / c) + b1[4 * k + 1]) + acc[4 * k + 1];
      r.z = ((sv.z / c) + b1[4 * k + 2]) + acc[4 * k + 2];
      r.w = ((sv.w / c) + b1[4 * k + 3]) + acc[4 * k + 3];
      r.x = (r.x >= 0.f) ? r.x : 0.01f * r.x;
      r.y = (r.y >= 0.f) ? r.y : 0.01f * r.y;
      r.z = (r.z >= 0.f) ? r.z : 0.01f * r.z;
      r.w = (r.w >= 0.f) ? r.w : 0.01f * r.w;
      h4[k] = r;
    }
  }
}

// layer2 = R13-PROVEN readlane version VERBATIM (measured optimum 54us).
#define L2_BLOCKS 1250
#define L2_NPW    20
__global__ __launch_bounds__(256) void k_layer2(
    float* __restrict__ A, float* __restrict__ B, const int* __restrict__ cnt,
    const float* __restrict__ W2l, const float* __restrict__ W2r,
    const float* __restrict__ b2)
{
  int lane = threadIdx.x & 63;
  int gw = blockIdx.x * 4 + (threadIdx.x >> 6);
  float wl[32], wr[32];
#pragma unroll
  for (int f = 0; f < 32; ++f) { wl[f] = W2l[lane * 32 + f]; wr[f] = W2r[lane * 32 + f]; }
  float bb = b2[lane];
  int n0 = gw * L2_NPW;
#pragma unroll 1
  for (int i = n0; i < n0 + L2_NPW; ++i) {
    float c = fmaxf((float)cnt[i], 1.f);
    float vin;
    if (lane < 32) vin = B[(size_t)i * 32 + lane] / c;
    else           vin = A[(size_t)i * 32 + (lane - 32)];
    float acc = 0.f, acc2 = 0.f;
#pragma unroll
    for (int f = 0; f < 32; ++f) {
      acc  += bcastf(vin, f)      * wl[f];
      acc2 += bcastf(vin, 32 + f) * wr[f];
    }
    float t = (acc + bb) + acc2;
    float s = t * t;
#pragma unroll
    for (int o = 32; o > 0; o >>= 1) s += __shfl_xor(s, o);
    float g = t / fmaxf(sqrtf(s), 1e-12f);
    if (lane < 32) A[(size_t)i * 32 + lane]        = g;
    else           B[(size_t)i * 32 + (lane - 32)] = g;
  }
}

// ---------------- KG phase (R26-proven, verbatim) ----------------

__device__ inline float kg_score_lds(const float* __restrict__ row,
                                     const float* sp, const float* su)
{
  float acc = 0.f;
#pragma unroll
  for (int d = 0; d < 64; ++d) {
    float t = sp[d] * row[d];
    t = (t >= 0.f) ? t : 0.01f * t;
    acc += t * su[d];
  }
  return acc;
}

__device__ inline float wave_softmax(float acc)
{
  float m = acc;
#pragma unroll
  for (int o = 32; o > 0; o >>= 1) m = fmaxf(m, __shfl_xor(m, o));
  float e = expf(acc - m);
  float Z = e;
#pragma unroll
  for (int o = 32; o > 0; o >>= 1) Z += __shfl_xor(Z, o);
  return e / Z;
}

__device__ inline void load_row(const float* glo, const float* ghi, int node,
                                int lane, float* smem)
{
  smem[lane] = (lane < 32) ? glo[(size_t)node * 32 + lane]
                           : ghi[(size_t)node * 32 + (lane - 32)];
}

// stage 64 neighbor rows (nb per-lane) into sn[64][65], coalesced.
__device__ inline void stage_rows(const float* __restrict__ glo,
                                  const float* __restrict__ ghi,
                                  int nb, int lane, float* sn)
{
#pragma unroll
  for (int j = 0; j < 64; ++j) {
    int rj = __builtin_amdgcn_readlane(nb, j);
    float v = (lane < 32) ? glo[(size_t)rj * 32 + lane]
                          : ghi[(size_t)rj * 32 + (lane - 32)];
    sn[j * 65 + lane] = v;
  }
}

// R26: fused KG selection kernel.  blocks [0,1024): argmax phase (old
// k_kg_argmax verbatim) followed in-register by topk2 var=0 (pidx=nbr=sel,
// a-keys, writes candA + logA + one_hop_log).  blocks [1024,2048): old
// topk2 var=1 verbatim (pidx=pvec, nbr=u, c-keys, writes candB).
__global__ __launch_bounds__(64) void k_kg_fused(
    const float* __restrict__ glo, const float* __restrict__ ghi,
    const int* __restrict__ users, const int* __restrict__ pvec,
    const int* __restrict__ adj,
    unsigned a1a, unsigned a1b, unsigned a2a, unsigned a2b,
    unsigned c1a, unsigned c1b, unsigned c2a, unsigned c2b,
    int* __restrict__ candA, float* __restrict__ logA,
    int* __restrict__ candB, float* __restrict__ one_hop_log)
{
  int b = blockIdx.x & (BATCH - 1);
  int var = blockIdx.x >> 10;
  int lane = threadIdx.x;
  int u = users[b];
  __shared__ float su[64], sp[64];
  __shared__ float sn[64 * 65];
  load_row(glo, ghi, u, lane, su);

  if (var == 1) {
    // ---- old topk2 var=1 path (pos2) ----
    int pidx = pvec[b];
    load_row(glo, ghi, pidx, lane, sp);
    int nb = adj[(size_t)u * 64 + lane];
    stage_rows(glo, ghi, nb, lane, sn);
    __syncthreads();
    float sm = wave_softmax(kg_score_lds(sn + lane * 65, sp, su));
    int r = 0;
#pragma unroll
    for (int j = 0; j < 64; ++j) {
      float sj = bcastf(sm, j);
      if (sj > sm || (sj == sm && j < lane)) ++r;
    }
    if (r < 32) {
      int cand = nb;
      unsigned jj = (unsigned)(b * 32 + r);
      unsigned h0, h1, l0, l1;
      threefry2x32(c1a, c1b, 0u, jj, &h0, &h1);
      threefry2x32(c2a, c2b, 0u, jj, &l0, &l1);
      unsigned hi = h0 ^ h1, lo = l0 ^ l1;
      unsigned rnd = ((hi % SPAN) * MULT + (lo % SPAN)) % SPAN;
      if (cand > 39999 || cand < 0) cand = (int)rnd;
      candB[b * 32 + r] = cand;
    }
  } else {
    // ---- phase 1: argmax (old k_kg_argmax verbatim) ----
    int pb = pvec[b];
    load_row(glo, ghi, pb, lane, sp);
    int nb = adj[(size_t)pb * 64 + lane];
    stage_rows(glo, ghi, nb, lane, sn);
    __syncthreads();
    float sm = wave_softmax(kg_score_lds(sn + lane * 65, sp, su));
    float v = sm; int i = lane;
#pragma unroll
    for (int o = 32; o > 0; o >>= 1) {
      float ov = __shfl_xor(v, o); int oi = __shfl_xor(i, o);
      if (ov > v || (ov == v && oi < i)) { v = ov; i = oi; }
    }
    float smw = __shfl(sm, i);
    int sel = __shfl(nb, i);
    if (lane == 0) one_hop_log[b] = logf(smw);
    // ---- phase 2: topk2 var=0 with pidx = nbr = sel ----
    __syncthreads();
    load_row(glo, ghi, sel, lane, sp);
    int nb2 = adj[(size_t)sel * 64 + lane];
    stage_rows(glo, ghi, nb2, lane, sn);
    __syncthreads();
    float sm2 = wave_softmax(kg_score_lds(sn + lane * 65, sp, su));
    int r = 0;
#pragma unroll
    for (int j = 0; j < 64; ++j) {
      float sj = bcastf(sm2, j);
      if (sj > sm2 || (sj == sm2 && j < lane)) ++r;
    }
    if (r < 32) {
      int cand = nb2;
      logA[b * 32 + r] = logf(sm2);
      unsigned jj = (unsigned)(b * 32 + r);
      unsigned h0, h1, l0, l1;
      threefry2x32(a1a, a1b, 0u, jj, &h0, &h1);
      threefry2x32(a2a, a2b, 0u, jj, &l0, &l1);
      unsigned hi = h0 ^ h1, lo = l0 ^ l1;
      unsigned rnd = ((hi % SPAN) * MULT + (lo % SPAN)) % SPAN;
      if (cand > 39999 || cand < 0) cand = (int)rnd;
      candA[b * 32 + r] = cand;
    }
  }
}

// R16: prune with LDS-staged disc rows (dp rows j<32, dn rows j>=32).
__global__ __launch_bounds__(64) void k_kg_prune(
    const float* __restrict__ disc, const int* __restrict__ users,
    const int* __restrict__ cand, const float* __restrict__ two_log,
    const int* __restrict__ pos2, const float* __restrict__ one_log,
    float* __restrict__ out, int k, int* __restrict__ p_next)
{
  int b = blockIdx.x, lane = threadIdx.x;
  __shared__ float su[64];
  __shared__ float sd[64 * 65];
  su[lane] = disc[(size_t)users[b] * 64 + lane];
  int pr = (lane < 32) ? pos2[b * 32 + lane] : cand[b * 32 + (lane - 32)];
#pragma unroll
  for (int j = 0; j < 64; ++j) {
    int rj = __builtin_amdgcn_readlane(pr, j);
    sd[j * 65 + lane] = disc[(size_t)rj * 64 + lane];
  }
  __syncthreads();
  float r = 1e30f;
  if (lane < 32) {
    const float* dp = sd + lane * 65;
    const float* dn = sd + (32 + lane) * 65;
    float acc = 0.f;
#pragma unroll
    for (int d = 0; d < 64; ++d) acc += su[d] * (dp[d] - dn[d]);
    r = acc;
  }
  float v = r; int i = lane;
#pragma unroll
  for (int o = 32; o > 0; o >>= 1) {
    float ov = __shfl_xor(v, o); int oi = __shfl_xor(i, o);
    if (ov < v || (ov == v && oi < i)) { v = ov; i = oi; }
  }
  if (lane == 0) {
    int gn = cand[b * 32 + i];
    float gl = two_log[b * 32 + i] + one_log[b];
    out[k * BATCH + b]             = (float)gn;
    out[2 * BATCH + k * BATCH + b] = gl;
    p_next[b] = gn;
  }
}

// ---------------- launch ----------------
extern "C" void kernel_launch(void* const* d_in, const int* in_sizes, int n_in,
                              void* d_out, int out_size, void* d_ws, size_t ws_size,
                              hipStream_t stream)
{
  const float* x    = (const float*)d_in[0];
  const float* W1l  = (const float*)d_in[1];
  const float* W1r  = (const float*)d_in[2];
  const float* b1   = (const float*)d_in[3];
  const float* W2l  = (const float*)d_in[4];
  const float* W2r  = (const float*)d_in[5];
  const float* b2   = (const float*)d_in[6];
  const float* disc = (const float*)d_in[7];
  const int*   users= (const int*)d_in[8];
  const int*   pos  = (const int*)d_in[9];
  const int*   adj  = (const int*)d_in[10];
  const int*   edge = (const int*)d_in[11];
  float* out = (float*)d_out;

  char* w = (char*)d_ws;
  // R24 layout (A disjoint so gemm can overlap the bucket chain):
  //   [0, 14,013,440)            csr (src ids grouped by dst, bucket gaps)
  //   [14,013,440, +400,000)     row_ptr (absolute)
  //   [14,413,440, +400,000)     deg
  //   [14,813,440, +2,048)       bbase
  //   [14,815,488, +2,048)       bcur
  //   [14,817,536, +12,800,000)  A  (gemm output; later layer1 output)
  //   [27,617,536, +14,013,440)  packed pairs; B ALIASES pairs[0:12.8M)
  //   [41,630,976, +405,504)     KG buffers   => NEED_FIX = 42,036,480
  const size_t NEED_FIX = 42036480;
  const size_t NEED_CSR = 39617792;   // fallback: scan-based tight layout
  float *A, *B;
  char* bb;

  if (ws_size >= NEED_FIX) {
    int*  csr   = (int*)(w);
    int*  rowp  = (int*)(w + 14013440);
    int*  deg   = (int*)(w + 14413440);
    int*  bbase = (int*)(w + 14813440);
    int*  bcur  = (int*)(w + 14815488);
    A = (float*)(w + 14817536);
    int*  pairs = (int*)(w + 27617536);
    B = (float*)(w + 27617536);
    bb = w + 41630976;
    k_init_buckets<<<2, 256, 0, stream>>>(bbase, bcur);
    // merged: scatter (blocks 0..SBLK) || gemm x@W1l^T -> A (blocks SBLK..)
    k_scatter_gemm<<<SBLK + DGB, 256, 0, stream>>>(edge, bcur, pairs, x, W1l, A);
    k_bucket_csr<<<NB_BKT, 1024, 0, stream>>>(bbase, bcur, pairs, csr, rowp, deg);
    // pairs dead from here; gather#1 may write B (aliases pairs)
    k_gather_csr<<<N_NODES / 8, 256, 0, stream>>>(rowp, deg, csr, A, B);
    k_layer1<<<DGB, 256, 0, stream>>>(B, deg, x, W1r, b1, A);
    k_gather_csr<<<N_NODES / 8, 256, 0, stream>>>(rowp, deg, csr, A, B);
    k_layer2<<<L2_BLOCKS, 256, 0, stream>>>(A, B, deg, W2l, W2r, b2);
  } else if (ws_size >= NEED_CSR) {
    // fallback: R13-style scan-based tight CSR (A aliases pairs; serial gemm)
    int*  csr   = (int*)(w);
    int*  rowp  = (int*)(w + 12800000);
    int*  deg   = (int*)(w + 13200000);
    int*  bhist = (int*)(w + 13600000);
    int*  bbase = (int*)(w + 13604096);
    int*  bcur  = (int*)(w + 13608192);
    int*  pairs = (int*)(w + 13612288);
    A = (float*)(w + 13612288);
    B = (float*)(w + 26412288);
    bb = w + 39212288;
    hipMemsetAsync(bhist, 0, 4096, stream);
    k_bucket_hist<<<SBLK, 256, 0, stream>>>(edge, bhist);
    k_scan_buckets<<<1, 512, 0, stream>>>(bhist, bbase, bcur);
    k_bucket_scatter<<<SBLK, 256, 0, stream>>>(edge, bcur, pairs);
    k_bucket_csr<<<NB_BKT, 1024, 0, stream>>>(bbase, bcur, pairs, csr, rowp, deg);
    k_gemm64x32<<<DGB, 256, 0, stream>>>(x, W1l, A);
    k_gather_csr<<<N_NODES / 8, 256, 0, stream>>>(rowp, deg, csr, A, B);
    k_layer1<<<DGB, 256, 0, stream>>>(B, deg, x, W1r, b1, A);
    k_gather_csr<<<N_NODES / 8, 256, 0, stream>>>(rowp, deg, csr, A, B);
    k_layer2<<<L2_BLOCKS, 256, 0, stream>>>(A, B, deg, W2l, W2r, b2);
  } else {
    // fallback: proven atomic-scatter path (R4)
    int* cnt = (int*)w;
    A = (float*)(w + 409600);
    B = (float*)(w + 13209600);
    bb = w + 26009600;
    hipMemsetAsync(cnt, 0, 400000, stream);
    hipMemsetAsync(B, 0, 12800000, stream);
    k_gemm64x32<<<DGB, 256, 0, stream>>>(x, W1l, A);
    k_scatter<<<N_EDGES / 8, 256, 0, stream>>>(edge, A, B, cnt);
    k_layer1<<<DGB, 256, 0, stream>>>(B, cnt, x, W1r, b1, A);
    hipMemsetAsync(B, 0, 12800000, stream);
    k_scatter<<<N_EDGES / 8, 256, 0, stream>>>(edge, A, B, nullptr);
    k_layer2<<<L2_BLOCKS, 256, 0, stream>>>(A, B, cnt, W2l, W2r, b2);
  }

  int*   p_cur       = (int*)(bb);
  float* one_hop_log = (float*)(bb + 8192);
  int*   cand        = (int*)(bb + 12288);
  float* two_log     = (float*)(bb + 143360);
  int*   pos2        = (int*)(bb + 274432);

  // --- KG walk, K_STEP = 2 (R26: fused argmax+topk per k) ---
  for (int k = 0; k < 2; ++k) {
    unsigned f0, f1, a1a, a1b, a2a, a2b, c1a, c1b, c2a, c2b;
    threefry2x32(0u, 123u, 0u, (unsigned)(2 * k), &f0, &f1);
    threefry2x32(f0, f1, 0u, 0u, &a1a, &a1b);
    threefry2x32(f0, f1, 0u, 1u, &a2a, &a2b);
    threefry2x32(0u, 123u, 0u, (unsigned)(2 * k + 1), &f0, &f1);
    threefry2x32(f0, f1, 0u, 0u, &c1a, &c1b);
    threefry2x32(f0, f1, 0u, 1u, &c2a, &c2b);

    const int* pvec = (k == 0) ? pos : p_cur;
    k_kg_fused<<<2 * BATCH, 64, 0, stream>>>(A, B, users, pvec, adj,
                                             a1a, a1b, a2a, a2b, c1a, c1b, c2a, c2b,
                                             cand, two_log, pos2, one_hop_log);
    k_kg_prune<<<BATCH, 64, 0, stream>>>(disc, users, cand, two_log, pos2,
                                         one_hop_log, out, k, p_cur);
  }
}